// Round 16
// baseline (11969.772 us; speedup 1.0000x reference)
//
#include <hip/hip_runtime.h>

#define DEVFN __device__ __forceinline__

constexpr int V=32000, E=512, H=512, B=16, K=8, S=50, T=40, N=128;
constexpr int SOS=2, EOS=3, UNK=0, PAD=1, MIN_LEN=3;
constexpr float DD=0.1f;
constexpr float FNEG=-1e20f;

constexpr long long PROBS_ELEMS = 163840000LL; // T*N*V
constexpr int TOK_OUT_OFF = 163840000;
constexpr int BS_OUT_OFF  = 163845120;

// scratch offsets (floats) inside d_out's probs region (re-zeroed at the end)
constexpr int LOGITS_O = 0;          // N*V
constexpr int WTOUT_O  = 4200000;    // 512*32000 transposed
constexpr int WTEIH_O  = 20600000;   // [512][1536] transposed
constexpr int WTEHH_O  = 21400000;
constexpr int WTDIH_O  = 22200000;
constexpr int WTDHH_O  = 23000000;
constexpr int WTATT_O  = 23800000;   // [512][512] transposed
constexpr int WTCMB_O  = 24100000;   // [1024][512] transposed
constexpr int WTBRG_O  = 24700000;   // [512][512] transposed
constexpr int ENC_O    = 25000000;   // S*B*H
constexpr int HST_O    = 25500000;   // 2*B*H
constexpr int HID_O    = 25520000;   // N*H
constexpr int HNEW_O   = 25600000;   // N*H
constexpr int CTX_O    = 25680000;   // N*H
constexpr int OVEC_O   = 25760000;   // N*H
constexpr int TOK0_O   = 25940000;   // T*N ints
constexpr int TOK1_O   = 25950000;
constexpr int BS0_O    = 25960000;   // T*N floats
constexpr int BS1_O    = 25970000;
constexpr int END_O    = 25980000;   // N ints
constexpr int LTOK_O   = 25990000;   // N ints
constexpr int PART_O   = 26000000;   // 128 rows x 4 quarters x 20 floats

DEVFN float sigm(float x){ return 1.0f/(1.0f + expf(-x)); }

// ---------------- transpose: in[R][C] -> out[C][R] ----------------
__global__ void tr_k(const float* __restrict__ in, float* __restrict__ out, int R, int C){
  __shared__ float t[32][33];
  int bx = blockIdx.x, by = blockIdx.y;
  int x = threadIdx.x & 31, y0 = threadIdx.x >> 5;
  for (int yy = y0; yy < 32; yy += 8){
    t[yy][x] = in[(long long)(by*32+yy)*C + bx*32 + x];
  }
  __syncthreads();
  for (int yy = y0; yy < 32; yy += 8){
    out[(long long)(bx*32+yy)*R + by*32 + x] = t[x][yy];
  }
}

// ---------------- init ----------------
__global__ void init_k(float* sc){
  int idx = blockIdx.x*256 + threadIdx.x;
  int* tok0 = (int*)(sc + TOK0_O);
  float* bs0 = sc + BS0_O;
  if (idx < T*N){
    tok0[idx] = (idx < N) ? SOS : 0;
    bs0[idx]  = (idx < N && (idx & 7)) ? FNEG : 0.0f;
  }
  if (idx < N){
    ((int*)(sc + END_O))[idx] = 0;
    ((int*)(sc + LTOK_O))[idx] = SOS;
  }
  if (idx < 2*B*H) sc[HST_O + idx] = 0.0f;
}

// ---------------- zero the probs region (proven) ----------------
__global__ void zero_k(float4* __restrict__ p){
  long long idx = (long long)blockIdx.x*256 + threadIdx.x;
  long long stride = (long long)gridDim.x*256;
  const long long n4 = PROBS_ELEMS/4;
  float4 z; z.x=0.f; z.y=0.f; z.z=0.f; z.w=0.f;
  for (long long u = idx; u < n4; u += stride) p[u] = z;
}

// ---------------- encoder one step (proven R12) ----------------
__global__ __launch_bounds__(384) void enc2_k(const int* __restrict__ src, const int* __restrict__ srclen,
    const float* __restrict__ embed, const float* __restrict__ wtih, const float* __restrict__ wthh,
    const float* __restrict__ bih, const float* __restrict__ bhh, float* sc, int t){
  int ic = blockIdx.x;
  int b  = blockIdx.y;
  int tid = threadIdx.x;
  int p = tid >> 6;
  int il = tid & 63;
  int i = ic*64 + il;
  __shared__ __align__(16) float e[512];
  __shared__ __align__(16) float h[512];
  __shared__ float gsh[6][64];
  const float* hsrc = sc + HST_O + (t&1)*B*H + b*H;
  float* hdst = sc + HST_O + ((t&1)^1)*B*H + b*H;
  int tok = src[t*B + b];
  for (int u = tid; u < 512; u += 384){
    e[u] = embed[(long long)tok*E + u];
    h[u] = hsrc[u];
  }
  __syncthreads();
  float acc = 0.0f;
  if (p < 3){
    const float* w = wtih + p*512 + i;
    for (int k=0;k<512;k++) acc += e[k]*w[(long long)k*1536];
  } else {
    const float* w = wthh + (p-3)*512 + i;
    for (int k=0;k<512;k++) acc += h[k]*w[(long long)k*1536];
  }
  gsh[p][il] = acc;
  __syncthreads();
  if (tid < 64){
    int ii = ic*64 + tid;
    float r = sigm(gsh[0][tid] + bih[ii] + gsh[3][tid] + bhh[ii]);
    float z = sigm(gsh[1][tid] + bih[512+ii] + gsh[4][tid] + bhh[512+ii]);
    float nn = tanhf(gsh[2][tid] + bih[1024+ii] + r*(gsh[5][tid] + bhh[1024+ii]));
    float hnew = (1.0f - z)*nn + z*h[ii];
    float hout = (t < srclen[b]) ? hnew : h[ii];
    hdst[ii] = hout;
    sc[ENC_O + ((long long)t*B + b)*H + ii] = hout;
  }
}

// ---------------- bridge + repeat K (proven) ----------------
__global__ __launch_bounds__(256) void bridge_k(const float* __restrict__ wtb, const float* __restrict__ bb, float* sc){
  int b = blockIdx.x; int tid = threadIdx.x;
  __shared__ __align__(16) float hf[512];
  const float* hsrc = sc + HST_O + (S&1)*B*H + b*H;
  ((float2*)hf)[tid] = ((const float2*)hsrc)[tid];
  __syncthreads();
  for (int ii=0; ii<2; ii++){
    int i = tid + ii*256;
    float acc = bb[i];
    for (int k=0;k<512;k++) acc += hf[k]*wtb[(long long)k*512 + i];
    float hb = tanhf(acc);
    for (int q=0;q<K;q++) sc[HID_O + ((long long)(b*K+q))*H + i] = hb;
  }
}

// ---------------- decoder GRU: 4 beams/block (proven R11) ----------------
__global__ __launch_bounds__(256) void grudec_k(const float* __restrict__ embed,
     const float* __restrict__ wtih, const float* __restrict__ wthh,
     const float* __restrict__ bih, const float* __restrict__ bhh, float* sc){
  int il = threadIdx.x & 63, n = threadIdx.x >> 6;
  int i = blockIdx.x*64 + il;
  int nb = blockIdx.y*4;
  __shared__ __align__(16) float e4[4][512];
  __shared__ __align__(16) float hp4[4][512];
  const int* ltok = (const int*)(sc + LTOK_O);
  for (int u = threadIdx.x; u < 4*128; u += 256){
    int r = u >> 7, c = u & 127;
    ((float4*)e4[r])[c]  = ((const float4*)(embed + (long long)ltok[nb+r]*E))[c];
    ((float4*)hp4[r])[c] = ((const float4*)(sc + HID_O + (long long)(nb+r)*H))[c];
  }
  __syncthreads();
  float ar=0,az=0,an=0,hr=0,hz=0,hn=0;
  for (int k=0;k<512;k++){
    const float* wi = wtih + (long long)k*1536;
    const float* wh = wthh + (long long)k*1536;
    float wr=wi[i], wz=wi[512+i], wn=wi[1024+i];
    float ur=wh[i], uz=wh[512+i], un=wh[1024+i];
    float e0=e4[n][k], p0=hp4[n][k];
    ar+=e0*wr; az+=e0*wz; an+=e0*wn; hr+=p0*ur; hz+=p0*uz; hn+=p0*un;
  }
  float br=bih[i], bz=bih[512+i], bn=bih[1024+i];
  float cr=bhh[i], cz=bhh[512+i], cn=bhh[1024+i];
  float r = sigm(ar+br+hr+cr);
  float z = sigm(az+bz+hz+cz);
  float nn = tanhf(an+bn + r*(hn+cn));
  sc[HNEW_O + (long long)(nb+n)*H + i] = (1.0f-z)*nn + z*hp4[n][i];
}

// ---------------- attention (q computed in-block; R6-proven fusion class) ----------------
// grid (2,128): x = ctx half, y = row. q per-output FMA order identical to old qgemm_k.
__global__ __launch_bounds__(256) void att_k(const int* __restrict__ srclen,
    const float* __restrict__ wta, float* sc){
  int hc = blockIdx.x;
  int n = blockIdx.y; int g = n >> 3;
  int tid = threadIdx.x, lane = tid & 63, wave = tid >> 6;
  __shared__ __align__(16) float h[512];
  __shared__ __align__(16) float q[512];
  __shared__ float al[64];
  if (tid < 128) ((float4*)h)[tid] = ((const float4*)(sc + HNEW_O + (long long)n*H))[tid];
  __syncthreads();
  for (int ii=0; ii<2; ii++){
    int i = tid + ii*256;
    float a = 0;
    for (int k=0;k<512;k++) a += h[k]*wta[(long long)k*512 + i];
    q[i] = a;
  }
  __syncthreads();
  const float* enc = sc + ENC_O;
  for (int s = wave; s < S; s += 4){
    const float* er = enc + ((long long)s*B + g)*H;
    float p = 0;
    #pragma unroll
    for (int j=0;j<8;j++) p += q[lane + 64*j]*er[lane + 64*j];
    #pragma unroll
    for (int off=32; off; off>>=1) p += __shfl_xor(p, off, 64);
    if (lane==0) al[s] = p;
  }
  __syncthreads();
  if (wave==0){
    int len = srclen[g];
    float v = (lane < S && lane < len) ? al[lane] : -1e9f;
    float m = v;
    #pragma unroll
    for (int off=32; off; off>>=1) m = fmaxf(m, __shfl_xor(m, off, 64));
    float ee = (lane < S) ? expf(v - m) : 0.0f;
    float ssum = ee;
    #pragma unroll
    for (int off=32; off; off>>=1) ssum += __shfl_xor(ssum, off, 64);
    if (lane < S) al[lane] = ee/ssum;
  }
  __syncthreads();
  {
    int i = hc*256 + tid;
    float acc = 0;
    for (int s=0;s<S;s++) acc += al[s]*enc[((long long)s*B+g)*H + i];
    sc[CTX_O + (long long)n*H + i] = acc;
  }
}

// ---------------- comb: 4 rows/block (proven R11) ----------------
__global__ __launch_bounds__(256) void comb_k(const float* __restrict__ wtc, const float* __restrict__ cb, float* sc){
  int il = threadIdx.x & 63, n = threadIdx.x >> 6;
  int i = blockIdx.x*64 + il;
  int nb = blockIdx.y*4;
  __shared__ __align__(16) float hn4[4][512];
  __shared__ __align__(16) float cx4[4][512];
  for (int u = threadIdx.x; u < 4*128; u += 256){
    int r = u>>7, c = u&127;
    ((float4*)hn4[r])[c] = ((const float4*)(sc + HNEW_O + (long long)(nb+r)*H))[c];
    ((float4*)cx4[r])[c] = ((const float4*)(sc + CTX_O + (long long)(nb+r)*H))[c];
  }
  __syncthreads();
  float a0=cb[i];
  for (int k=0;k<512;k++){
    float w = wtc[(long long)k*512 + i];
    a0 += hn4[n][k]*w;
  }
  for (int k=0;k<512;k++){
    float w = wtc[(long long)(512+k)*512 + i];
    a0 += cx4[n][k]*w;
  }
  sc[OVEC_O + (long long)(nb+n)*H + i] = tanhf(a0);
}

// ---------------- logits (round-8 proven: register prefetch + store) ----------------
__global__ __launch_bounds__(256) void logits_k(const float* __restrict__ wto, const float* __restrict__ ob, float* sc){
  int v = blockIdx.x*1024 + threadIdx.x*4;
  int nb = blockIdx.y*16;
  __shared__ __align__(16) float o16[16][512];
  for (int u = threadIdx.x; u < 16*128; u += 256){
    int r = u>>7, c = u&127;
    ((float4*)o16[r])[c] = ((const float4*)(sc + OVEC_O + (long long)(nb + r)*H))[c];
  }
  __syncthreads();
  if (v >= V) return;
  float acc[16][4] = {};
  const float* wp = wto + v;
  float4 c0 = *((const float4*)(wp));
  float4 c1 = *((const float4*)(wp + V));
  float4 c2 = *((const float4*)(wp + 2LL*V));
  float4 c3 = *((const float4*)(wp + 3LL*V));
  for (int k=0;k<512;k+=4){
    float4 n0v=c0, n1v=c1, n2v=c2, n3v=c3;
    if (k < 508){
      const float* np_ = wp + (long long)(k+4)*V;
      n0v = *((const float4*)(np_));
      n1v = *((const float4*)(np_ + V));
      n2v = *((const float4*)(np_ + 2LL*V));
      n3v = *((const float4*)(np_ + 3LL*V));
    }
    #pragma unroll
    for (int j=0;j<16;j++){
      float4 o = *((const float4*)&o16[j][k]);
      acc[j][0] += o.x*c0.x + o.y*c1.x + o.z*c2.x + o.w*c3.x;
      acc[j][1] += o.x*c0.y + o.y*c1.y + o.z*c2.y + o.w*c3.y;
      acc[j][2] += o.x*c0.z + o.y*c1.z + o.z*c2.z + o.w*c3.z;
      acc[j][3] += o.x*c0.w + o.y*c1.w + o.z*c2.w + o.w*c3.w;
    }
    c0=n0v; c1=n1v; c2=n2v; c3=n3v;
  }
  float4 bbv = *((const float4*)(ob + v));
  #pragma unroll
  for (int j=0;j<16;j++){
    float4 r;
    r.x = acc[j][0]+bbv.x; r.y = acc[j][1]+bbv.y; r.z = acc[j][2]+bbv.z; r.w = acc[j][3]+bbv.w;
    *((float4*)(sc + LOGITS_O + (long long)(nb+j)*V + v)) = r;
  }
}

// ---------------- topk partial: proven 2-pass body over QUARTER rows (proven R15) ----------------
__global__ __launch_bounds__(256) void topkp_k(float* sc, int t){
  int hc = blockIdx.x, n = blockIdx.y, tid = threadIdx.x;
  const float4* row4 = (const float4*)(sc + LOGITS_O + (long long)n*V);
  const int u0 = hc*2000, u1 = u0 + 2000;
  __shared__ float rv[256];
  __shared__ float mv[256][8];
  __shared__ int   mi[256][8];
  float lm = -INFINITY;
  for (int u = u0 + tid; u < u1; u += 256){
    float4 x = row4[u];
    lm = fmaxf(lm, fmaxf(fmaxf(x.x,x.y), fmaxf(x.z,x.w)));
  }
  rv[tid] = lm; __syncthreads();
  for (int s2=128; s2; s2>>=1){ if (tid<s2) rv[tid]=fmaxf(rv[tid],rv[tid+s2]); __syncthreads(); }
  float rmax = rv[0]; __syncthreads();
  float tv[8]; int ti[8];
  #pragma unroll
  for (int j=0;j<8;j++){ tv[j] = -INFINITY; ti[j] = V; }
  float ls = 0;
  for (int u = u0 + tid; u < u1; u += 256){
    float4 x = row4[u];
    ls += expf(x.x-rmax)+expf(x.y-rmax)+expf(x.z-rmax)+expf(x.w-rmax);
    #pragma unroll
    for (int c=0;c<4;c++){
      int idx = u*4+c;
      float val = (c==0)?x.x:(c==1)?x.y:(c==2)?x.z:x.w;
      bool masked = (idx==UNK) || (idx==EOS && t<=MIN_LEN);
      if (!masked && val > tv[7]){
        tv[7] = val; ti[7] = idx;
        #pragma unroll
        for (int j=7;j>0;j--){
          if (tv[j] > tv[j-1]){
            float tf=tv[j]; tv[j]=tv[j-1]; tv[j-1]=tf;
            int tii=ti[j]; ti[j]=ti[j-1]; ti[j-1]=tii;
          }
        }
      }
    }
  }
  rv[tid] = ls;
  #pragma unroll
  for (int j=0;j<8;j++){ mv[tid][j]=tv[j]; mi[tid][j]=ti[j]; }
  __syncthreads();
  for (int s2=128; s2; s2>>=1){ if (tid<s2) rv[tid]+=rv[tid+s2]; __syncthreads(); }
  for (int s2=128; s2; s2>>=1){
    if (tid < s2){
      float ra[8]; int ri_[8];
      int pa=0, pb=0;
      #pragma unroll
      for (int o=0;o<8;o++){
        float va = mv[tid][pa<8?pa:7];   int xa = mi[tid][pa<8?pa:7];
        float vb = mv[tid+s2][pb<8?pb:7]; int xb = mi[tid+s2][pb<8?pb:7];
        bool ava = (pa<8), avb = (pb<8);
        bool ta;
        if (!ava) ta = false;
        else if (!avb) ta = true;
        else ta = (va > vb) || (va == vb && xa < xb);
        ra[o] = ta ? va : vb; ri_[o] = ta ? xa : xb;
        pa += ta ? 1 : 0; pb += ta ? 0 : 1;
      }
      #pragma unroll
      for (int o=0;o<8;o++){ mv[tid][o]=ra[o]; mi[tid][o]=ri_[o]; }
    }
    __syncthreads();
  }
  if (tid == 0){
    float* pp = sc + PART_O + ((long long)n*4 + hc)*20;
    #pragma unroll
    for (int o=0;o<8;o++){ pp[o] = mv[0][o]; ((int*)pp)[8+o] = mi[0][o]; }
    pp[16] = rmax; pp[17] = rv[0];
  }
}

// ---------------- beam (proven R15: 4-partial merge prologue) ----------------
__global__ __launch_bounds__(64) void beam_k(float* sc, int t){
  int b = blockIdx.x, lane = threadIdx.x;
  int* endp = (int*)(sc + END_O);
  int* ltok = (int*)(sc + LTOK_O);
  const int* tokc; int* tokn; const float* bsc; float* bsn;
  if (t & 1){ tokc=(const int*)(sc+TOK0_O); tokn=(int*)(sc+TOK1_O); bsc=sc+BS0_O; bsn=sc+BS1_O; }
  else      { tokc=(const int*)(sc+TOK1_O); tokn=(int*)(sc+TOK0_O); bsc=sc+BS1_O; bsn=sc+BS0_O; }
  __shared__ float tks[64]; __shared__ int tki[64];
  __shared__ float l1v[64]; __shared__ int l1i[64];
  __shared__ float l2v[64]; __shared__ int l2i[64];
  __shared__ int selp[8]; __shared__ int newtok[8]; __shared__ float newsc[8]; __shared__ int newend[8];
  if (lane < 8){
    const float* p0 = sc + PART_O + ((long long)(b*8+lane)*4 + 0)*20;
    const float* p1 = p0 + 20;
    const float* p2 = p0 + 40;
    const float* p3 = p0 + 60;
    float m0=p0[16], m1=p1[16], m2=p2[16], m3=p3[16];
    float gm = fmaxf(fmaxf(m0,m1), fmaxf(m2,m3));
    float ss = p0[17]*expf(m0-gm) + p1[17]*expf(m1-gm) + p2[17]*expf(m2-gm) + p3[17]*expf(m3-gm);
    float lsum = logf(ss);
    int base = lane*8;
    {
      int pa=0, pb=0;
      for (int o=0;o<8;o++){
        int ia = pa<8?pa:7, ib = pb<8?pb:7;
        float va = p0[ia]; int xa = ((const int*)p0)[8+ia];
        float vb = p1[ib]; int xb = ((const int*)p1)[8+ib];
        bool ta = (pa<8) && ((pb>=8) || (va > vb) || (va == vb && xa < xb));
        l1v[base+o] = ta?va:vb; l1i[base+o] = ta?xa:xb;
        pa += ta?1:0; pb += ta?0:1;
      }
    }
    {
      int pa=0, pb=0;
      for (int o=0;o<8;o++){
        int ia = pa<8?pa:7, ib = pb<8?pb:7;
        float va = p2[ia]; int xa = ((const int*)p2)[8+ia];
        float vb = p3[ib]; int xb = ((const int*)p3)[8+ib];
        bool ta = (pa<8) && ((pb>=8) || (va > vb) || (va == vb && xa < xb));
        l2v[base+o] = ta?va:vb; l2i[base+o] = ta?xa:xb;
        pa += ta?1:0; pb += ta?0:1;
      }
    }
    {
      int pa=0, pb=0;
      for (int o=0;o<8;o++){
        int ia = pa<8?pa:7, ib = pb<8?pb:7;
        float va = l1v[base+ia]; int xa = l1i[base+ia];
        float vb = l2v[base+ib]; int xb = l2i[base+ib];
        bool ta = (pa<8) && ((pb>=8) || (va > vb) || (va == vb && xa < xb));
        tks[base+o] = ((ta?va:vb) - gm) - lsum;
        tki[base+o] = ta?xa:xb;
        pa += ta?1:0; pb += ta?0:1;
      }
    }
  }
  __syncthreads();
  if (lane == 0){
    float tot[64]; float cur[64]; int tix[64];
    for (int k=0;k<8;k++){
      float tp = 0;
      for (int u=0;u<T;u++) tp += bsc[u*N + b*8 + k];
      int ek = endp[b*8+k];
      for (int j=0;j<8;j++){
        float scv = tks[k*8 + j];
        if (t > 1) scv -= DD * (float)j;
        float fin = ek ? (-scv + (j==0 ? 0.0f : FNEG)) : 0.0f;
        tot[k*8+j] = (scv + tp) + fin;
        cur[k*8+j] = scv + fin;
        tix[k*8+j] = tki[k*8 + j];
      }
    }
    for (int q=0;q<8;q++){
      int best = 0; float bv = tot[0];
      for (int c=1;c<64;c++){
        if (tot[c] > bv){ bv = tot[c]; best = c; }
      }
      int p = best >> 3;
      int en = endp[b*8+p];
      int tk2 = tix[best];
      int lt = en ? PAD : tk2;
      selp[q] = p;
      newtok[q] = lt;
      newsc[q] = (lt != PAD) ? cur[best] : 0.0f;
      newend[q] = (en || lt == EOS) ? 1 : 0;
      tot[best] = -INFINITY;
    }
  }
  __syncthreads();
  for (int u = lane; u < T*8; u += 64){
    int tp2 = u >> 3, jp = u & 7;
    int p = selp[jp];
    tokn[tp2*N + b*8 + jp] = tokc[tp2*N + b*8 + p];
    bsn[tp2*N + b*8 + jp]  = bsc[tp2*N + b*8 + p];
  }
  __syncthreads();
  if (lane < 8){
    tokn[t*N + b*8 + lane] = newtok[lane];
    bsn[t*N + b*8 + lane]  = newsc[lane];
    ltok[b*8+lane] = newtok[lane];
    endp[b*8+lane] = newend[lane];
  }
  const float4* hsrc = (const float4*)(sc + HNEW_O + (long long)(b*8)*H);
  float4* hdst = (float4*)(sc + HID_O + (long long)(b*8)*H);
  for (int u = lane; u < 8*128; u += 64){
    int jp = u >> 7, c = u & 127;
    hdst[jp*128 + c] = hsrc[c];
  }
}

// ---------------- emit tokens + beam_scores (proven; ordered before zero_k) ----------------
__global__ void emit_k(float* out, float* sc){
  int idx = blockIdx.x*256 + threadIdx.x;
  if (idx < T*N){
    out[TOK_OUT_OFF + idx] = (float)(((const int*)(sc + TOK1_O))[idx]);
    out[BS_OUT_OFF + idx]  = sc[BS1_O + idx];
  }
}

extern "C" void kernel_launch(void* const* d_in, const int* in_sizes, int n_in,
                              void* d_out, int out_size, void* d_ws, size_t ws_size,
                              hipStream_t stream){
  const int*   src    = (const int*)d_in[0];
  const int*   srclen = (const int*)d_in[1];
  const float* embed  = (const float*)d_in[2];
  const float* eWih   = (const float*)d_in[3];
  const float* eWhh   = (const float*)d_in[4];
  const float* ebih   = (const float*)d_in[5];
  const float* ebhh   = (const float*)d_in[6];
  const float* brW    = (const float*)d_in[7];
  const float* brb    = (const float*)d_in[8];
  const float* dWih   = (const float*)d_in[9];
  const float* dWhh   = (const float*)d_in[10];
  const float* dbih   = (const float*)d_in[11];
  const float* dbhh   = (const float*)d_in[12];
  const float* attW   = (const float*)d_in[13];
  const float* cmbW   = (const float*)d_in[14];
  const float* cmbb   = (const float*)d_in[15];
  const float* outW   = (const float*)d_in[16];
  const float* outb   = (const float*)d_in[17];
  float* sc = (float*)d_out;

  tr_k<<<dim3(16,48),256,0,stream>>>(eWih, sc+WTEIH_O, 1536, 512);
  tr_k<<<dim3(16,48),256,0,stream>>>(eWhh, sc+WTEHH_O, 1536, 512);
  tr_k<<<dim3(16,48),256,0,stream>>>(dWih, sc+WTDIH_O, 1536, 512);
  tr_k<<<dim3(16,48),256,0,stream>>>(dWhh, sc+WTDHH_O, 1536, 512);
  tr_k<<<dim3(16,16),256,0,stream>>>(attW, sc+WTATT_O, 512, 512);
  tr_k<<<dim3(32,16),256,0,stream>>>(cmbW, sc+WTCMB_O, 512, 1024);
  tr_k<<<dim3(16,16),256,0,stream>>>(brW,  sc+WTBRG_O, 512, 512);
  tr_k<<<dim3(16,1000),256,0,stream>>>(outW, sc+WTOUT_O, 32000, 512);
  init_k<<<64,256,0,stream>>>(sc);

  for (int t=0; t<S; t++)
    enc2_k<<<dim3(8,16),384,0,stream>>>(src, srclen, embed, sc+WTEIH_O, sc+WTEHH_O, ebih, ebhh, sc, t);
  bridge_k<<<16,256,0,stream>>>(sc+WTBRG_O, brb, sc);

  for (int t=1; t<T; t++){
    grudec_k<<<dim3(8,32),256,0,stream>>>(embed, sc+WTDIH_O, sc+WTDHH_O, dbih, dbhh, sc);
    att_k<<<dim3(2,128),256,0,stream>>>(srclen, sc+WTATT_O, sc);
    comb_k<<<dim3(8,32),256,0,stream>>>(sc+WTCMB_O, cmbb, sc);
    logits_k<<<dim3(32,8),256,0,stream>>>(sc+WTOUT_O, outb, sc);
    topkp_k<<<dim3(4,128),256,0,stream>>>(sc, t);
    beam_k<<<16,64,0,stream>>>(sc, t);
  }

  emit_k<<<20,256,0,stream>>>((float*)d_out, sc);
  zero_k<<<2048,256,0,stream>>>((float4*)d_out);
}

// Round 17
// 11477.016 us; speedup vs baseline: 1.0429x; 1.0429x over previous
//
#include <hip/hip_runtime.h>

#define DEVFN __device__ __forceinline__

constexpr int V=32000, E=512, H=512, B=16, K=8, S=50, T=40, N=128;
constexpr int SOS=2, EOS=3, UNK=0, PAD=1, MIN_LEN=3;
constexpr float DD=0.1f;
constexpr float FNEG=-1e20f;

constexpr long long PROBS_ELEMS = 163840000LL; // T*N*V
constexpr int TOK_OUT_OFF = 163840000;
constexpr int BS_OUT_OFF  = 163845120;

// scratch offsets (floats) inside d_out's probs region (re-zeroed at the end)
constexpr int LOGITS_O = 0;          // N*V
constexpr int WTOUT_O  = 4200000;    // 512*32000 transposed
constexpr int WTEIH_O  = 20600000;   // [512][1536] transposed
constexpr int WTEHH_O  = 21400000;
constexpr int WTDIH_O  = 22200000;
constexpr int WTDHH_O  = 23000000;
constexpr int WTATT_O  = 23800000;   // [512][512] transposed
constexpr int WTCMB_O  = 24100000;   // [1024][512] transposed
constexpr int WTBRG_O  = 24700000;   // [512][512] transposed
constexpr int ENC_O    = 25000000;   // S*B*H
constexpr int HST_O    = 25500000;   // 2*B*H
constexpr int HID_O    = 25520000;   // N*H
constexpr int HNEW_O   = 25600000;   // N*H
constexpr int CTX_O    = 25680000;   // N*H
constexpr int OVEC_O   = 25760000;   // N*H
constexpr int QVEC_O   = 25840000;   // N*H
constexpr int TOK0_O   = 25940000;   // T*N ints
constexpr int TOK1_O   = 25950000;
constexpr int BS0_O    = 25960000;   // T*N floats
constexpr int BS1_O    = 25970000;
constexpr int END_O    = 25980000;   // N ints
constexpr int LTOK_O   = 25990000;   // N ints
constexpr int PART_O   = 26000000;   // 128 rows x 4 quarters x 20 floats

DEVFN float sigm(float x){ return 1.0f/(1.0f + expf(-x)); }

// ---------------- transpose: in[R][C] -> out[C][R] ----------------
__global__ void tr_k(const float* __restrict__ in, float* __restrict__ out, int R, int C){
  __shared__ float t[32][33];
  int bx = blockIdx.x, by = blockIdx.y;
  int x = threadIdx.x & 31, y0 = threadIdx.x >> 5;
  for (int yy = y0; yy < 32; yy += 8){
    t[yy][x] = in[(long long)(by*32+yy)*C + bx*32 + x];
  }
  __syncthreads();
  for (int yy = y0; yy < 32; yy += 8){
    out[(long long)(bx*32+yy)*R + by*32 + x] = t[x][yy];
  }
}

// ---------------- init ----------------
__global__ void init_k(float* sc){
  int idx = blockIdx.x*256 + threadIdx.x;
  int* tok0 = (int*)(sc + TOK0_O);
  float* bs0 = sc + BS0_O;
  if (idx < T*N){
    tok0[idx] = (idx < N) ? SOS : 0;
    bs0[idx]  = (idx < N && (idx & 7)) ? FNEG : 0.0f;
  }
  if (idx < N){
    ((int*)(sc + END_O))[idx] = 0;
    ((int*)(sc + LTOK_O))[idx] = SOS;
  }
  if (idx < 2*B*H) sc[HST_O + idx] = 0.0f;
}

// ---------------- zero the probs region (proven) ----------------
__global__ void zero_k(float4* __restrict__ p){
  long long idx = (long long)blockIdx.x*256 + threadIdx.x;
  long long stride = (long long)gridDim.x*256;
  const long long n4 = PROBS_ELEMS/4;
  float4 z; z.x=0.f; z.y=0.f; z.z=0.f; z.w=0.f;
  for (long long u = idx; u < n4; u += stride) p[u] = z;
}

// ---------------- encoder one step (proven R12) ----------------
__global__ __launch_bounds__(384) void enc2_k(const int* __restrict__ src, const int* __restrict__ srclen,
    const float* __restrict__ embed, const float* __restrict__ wtih, const float* __restrict__ wthh,
    const float* __restrict__ bih, const float* __restrict__ bhh, float* sc, int t){
  int ic = blockIdx.x;
  int b  = blockIdx.y;
  int tid = threadIdx.x;
  int p = tid >> 6;
  int il = tid & 63;
  int i = ic*64 + il;
  __shared__ __align__(16) float e[512];
  __shared__ __align__(16) float h[512];
  __shared__ float gsh[6][64];
  const float* hsrc = sc + HST_O + (t&1)*B*H + b*H;
  float* hdst = sc + HST_O + ((t&1)^1)*B*H + b*H;
  int tok = src[t*B + b];
  for (int u = tid; u < 512; u += 384){
    e[u] = embed[(long long)tok*E + u];
    h[u] = hsrc[u];
  }
  __syncthreads();
  float acc = 0.0f;
  if (p < 3){
    const float* w = wtih + p*512 + i;
    for (int k=0;k<512;k++) acc += e[k]*w[(long long)k*1536];
  } else {
    const float* w = wthh + (p-3)*512 + i;
    for (int k=0;k<512;k++) acc += h[k]*w[(long long)k*1536];
  }
  gsh[p][il] = acc;
  __syncthreads();
  if (tid < 64){
    int ii = ic*64 + tid;
    float r = sigm(gsh[0][tid] + bih[ii] + gsh[3][tid] + bhh[ii]);
    float z = sigm(gsh[1][tid] + bih[512+ii] + gsh[4][tid] + bhh[512+ii]);
    float nn = tanhf(gsh[2][tid] + bih[1024+ii] + r*(gsh[5][tid] + bhh[1024+ii]));
    float hnew = (1.0f - z)*nn + z*h[ii];
    float hout = (t < srclen[b]) ? hnew : h[ii];
    hdst[ii] = hout;
    sc[ENC_O + ((long long)t*B + b)*H + ii] = hout;
  }
}

// ---------------- bridge + repeat K (proven) ----------------
__global__ __launch_bounds__(256) void bridge_k(const float* __restrict__ wtb, const float* __restrict__ bb, float* sc){
  int b = blockIdx.x; int tid = threadIdx.x;
  __shared__ __align__(16) float hf[512];
  const float* hsrc = sc + HST_O + (S&1)*B*H + b*H;
  ((float2*)hf)[tid] = ((const float2*)hsrc)[tid];
  __syncthreads();
  for (int ii=0; ii<2; ii++){
    int i = tid + ii*256;
    float acc = bb[i];
    for (int k=0;k<512;k++) acc += hf[k]*wtb[(long long)k*512 + i];
    float hb = tanhf(acc);
    for (int q=0;q<K;q++) sc[HID_O + ((long long)(b*K+q))*H + i] = hb;
  }
}

// ---------------- decoder GRU: 4 beams/block (proven R11) ----------------
__global__ __launch_bounds__(256) void grudec_k(const float* __restrict__ embed,
     const float* __restrict__ wtih, const float* __restrict__ wthh,
     const float* __restrict__ bih, const float* __restrict__ bhh, float* sc){
  int il = threadIdx.x & 63, n = threadIdx.x >> 6;
  int i = blockIdx.x*64 + il;
  int nb = blockIdx.y*4;
  __shared__ __align__(16) float e4[4][512];
  __shared__ __align__(16) float hp4[4][512];
  const int* ltok = (const int*)(sc + LTOK_O);
  for (int u = threadIdx.x; u < 4*128; u += 256){
    int r = u >> 7, c = u & 127;
    ((float4*)e4[r])[c]  = ((const float4*)(embed + (long long)ltok[nb+r]*E))[c];
    ((float4*)hp4[r])[c] = ((const float4*)(sc + HID_O + (long long)(nb+r)*H))[c];
  }
  __syncthreads();
  float ar=0,az=0,an=0,hr=0,hz=0,hn=0;
  for (int k=0;k<512;k++){
    const float* wi = wtih + (long long)k*1536;
    const float* wh = wthh + (long long)k*1536;
    float wr=wi[i], wz=wi[512+i], wn=wi[1024+i];
    float ur=wh[i], uz=wh[512+i], un=wh[1024+i];
    float e0=e4[n][k], p0=hp4[n][k];
    ar+=e0*wr; az+=e0*wz; an+=e0*wn; hr+=p0*ur; hz+=p0*uz; hn+=p0*un;
  }
  float br=bih[i], bz=bih[512+i], bn=bih[1024+i];
  float cr=bhh[i], cz=bhh[512+i], cn=bhh[1024+i];
  float r = sigm(ar+br+hr+cr);
  float z = sigm(az+bz+hz+cz);
  float nn = tanhf(an+bn + r*(hn+cn));
  sc[HNEW_O + (long long)(nb+n)*H + i] = (1.0f-z)*nn + z*hp4[n][i];
}

// ---------------- q = h_new @ attn_W^T: 4 rows/block (proven R11) ----------------
__global__ __launch_bounds__(256) void qgemm_k(const float* __restrict__ wta, float* sc){
  int il = threadIdx.x & 63, n = threadIdx.x >> 6;
  int i = blockIdx.x*64 + il;
  int nb = blockIdx.y*4;
  __shared__ __align__(16) float hn4[4][512];
  for (int u = threadIdx.x; u < 4*128; u += 256){
    int r = u>>7, c = u&127;
    ((float4*)hn4[r])[c] = ((const float4*)(sc + HNEW_O + (long long)(nb+r)*H))[c];
  }
  __syncthreads();
  float a0=0;
  for (int k=0;k<512;k++){
    float w = wta[(long long)k*512 + i];
    a0 += hn4[n][k]*w;
  }
  sc[QVEC_O + (long long)(nb+n)*H + i] = a0;
}

// ---------------- attention: 2 blocks/row (proven R12) ----------------
__global__ __launch_bounds__(256) void att_k(const int* __restrict__ srclen, float* sc){
  int hc = blockIdx.x;
  int n = blockIdx.y; int g = n >> 3;
  int tid = threadIdx.x, lane = tid & 63, wave = tid >> 6;
  __shared__ __align__(16) float ql[512];
  __shared__ float al[64];
  if (tid < 128) ((float4*)ql)[tid] = ((const float4*)(sc + QVEC_O + (long long)n*H))[tid];
  __syncthreads();
  const float* enc = sc + ENC_O;
  for (int s = wave; s < S; s += 4){
    const float* er = enc + ((long long)s*B + g)*H;
    float p = 0;
    #pragma unroll
    for (int j=0;j<8;j++) p += ql[lane + 64*j]*er[lane + 64*j];
    #pragma unroll
    for (int off=32; off; off>>=1) p += __shfl_xor(p, off, 64);
    if (lane==0) al[s] = p;
  }
  __syncthreads();
  if (wave==0){
    int len = srclen[g];
    float v = (lane < S && lane < len) ? al[lane] : -1e9f;
    float m = v;
    #pragma unroll
    for (int off=32; off; off>>=1) m = fmaxf(m, __shfl_xor(m, off, 64));
    float ee = (lane < S) ? expf(v - m) : 0.0f;
    float ssum = ee;
    #pragma unroll
    for (int off=32; off; off>>=1) ssum += __shfl_xor(ssum, off, 64);
    if (lane < S) al[lane] = ee/ssum;
  }
  __syncthreads();
  {
    int i = hc*256 + tid;
    float acc = 0;
    for (int s=0;s<S;s++) acc += al[s]*enc[((long long)s*B+g)*H + i];
    sc[CTX_O + (long long)n*H + i] = acc;
  }
}

// ---------------- comb: 4 rows/block (proven R11) ----------------
__global__ __launch_bounds__(256) void comb_k(const float* __restrict__ wtc, const float* __restrict__ cb, float* sc){
  int il = threadIdx.x & 63, n = threadIdx.x >> 6;
  int i = blockIdx.x*64 + il;
  int nb = blockIdx.y*4;
  __shared__ __align__(16) float hn4[4][512];
  __shared__ __align__(16) float cx4[4][512];
  for (int u = threadIdx.x; u < 4*128; u += 256){
    int r = u>>7, c = u&127;
    ((float4*)hn4[r])[c] = ((const float4*)(sc + HNEW_O + (long long)(nb+r)*H))[c];
    ((float4*)cx4[r])[c] = ((const float4*)(sc + CTX_O + (long long)(nb+r)*H))[c];
  }
  __syncthreads();
  float a0=cb[i];
  for (int k=0;k<512;k++){
    float w = wtc[(long long)k*512 + i];
    a0 += hn4[n][k]*w;
  }
  for (int k=0;k<512;k++){
    float w = wtc[(long long)(512+k)*512 + i];
    a0 += cx4[n][k]*w;
  }
  sc[OVEC_O + (long long)(nb+n)*H + i] = tanhf(a0);
}

// ---------------- logits (round-8 proven: register prefetch + store) ----------------
__global__ __launch_bounds__(256) void logits_k(const float* __restrict__ wto, const float* __restrict__ ob, float* sc){
  int v = blockIdx.x*1024 + threadIdx.x*4;
  int nb = blockIdx.y*16;
  __shared__ __align__(16) float o16[16][512];
  for (int u = threadIdx.x; u < 16*128; u += 256){
    int r = u>>7, c = u&127;
    ((float4*)o16[r])[c] = ((const float4*)(sc + OVEC_O + (long long)(nb + r)*H))[c];
  }
  __syncthreads();
  if (v >= V) return;
  float acc[16][4] = {};
  const float* wp = wto + v;
  float4 c0 = *((const float4*)(wp));
  float4 c1 = *((const float4*)(wp + V));
  float4 c2 = *((const float4*)(wp + 2LL*V));
  float4 c3 = *((const float4*)(wp + 3LL*V));
  for (int k=0;k<512;k+=4){
    float4 n0v=c0, n1v=c1, n2v=c2, n3v=c3;
    if (k < 508){
      const float* np_ = wp + (long long)(k+4)*V;
      n0v = *((const float4*)(np_));
      n1v = *((const float4*)(np_ + V));
      n2v = *((const float4*)(np_ + 2LL*V));
      n3v = *((const float4*)(np_ + 3LL*V));
    }
    #pragma unroll
    for (int j=0;j<16;j++){
      float4 o = *((const float4*)&o16[j][k]);
      acc[j][0] += o.x*c0.x + o.y*c1.x + o.z*c2.x + o.w*c3.x;
      acc[j][1] += o.x*c0.y + o.y*c1.y + o.z*c2.y + o.w*c3.y;
      acc[j][2] += o.x*c0.z + o.y*c1.z + o.z*c2.z + o.w*c3.z;
      acc[j][3] += o.x*c0.w + o.y*c1.w + o.z*c2.w + o.w*c3.w;
    }
    c0=n0v; c1=n1v; c2=n2v; c3=n3v;
  }
  float4 bbv = *((const float4*)(ob + v));
  #pragma unroll
  for (int j=0;j<16;j++){
    float4 r;
    r.x = acc[j][0]+bbv.x; r.y = acc[j][1]+bbv.y; r.z = acc[j][2]+bbv.z; r.w = acc[j][3]+bbv.w;
    *((float4*)(sc + LOGITS_O + (long long)(nb+j)*V + v)) = r;
  }
}

// ---------------- topk partial: proven 2-pass body over QUARTER rows (proven R15) ----------------
__global__ __launch_bounds__(256) void topkp_k(float* sc, int t){
  int hc = blockIdx.x, n = blockIdx.y, tid = threadIdx.x;
  const float4* row4 = (const float4*)(sc + LOGITS_O + (long long)n*V);
  const int u0 = hc*2000, u1 = u0 + 2000;   // V/4 = 8000 float4s per row
  __shared__ float rv[256];
  __shared__ float mv[256][8];
  __shared__ int   mi[256][8];
  float lm = -INFINITY;
  for (int u = u0 + tid; u < u1; u += 256){
    float4 x = row4[u];
    lm = fmaxf(lm, fmaxf(fmaxf(x.x,x.y), fmaxf(x.z,x.w)));
  }
  rv[tid] = lm; __syncthreads();
  for (int s2=128; s2; s2>>=1){ if (tid<s2) rv[tid]=fmaxf(rv[tid],rv[tid+s2]); __syncthreads(); }
  float rmax = rv[0]; __syncthreads();
  float tv[8]; int ti[8];
  #pragma unroll
  for (int j=0;j<8;j++){ tv[j] = -INFINITY; ti[j] = V; }
  float ls = 0;
  for (int u = u0 + tid; u < u1; u += 256){
    float4 x = row4[u];
    ls += expf(x.x-rmax)+expf(x.y-rmax)+expf(x.z-rmax)+expf(x.w-rmax);
    #pragma unroll
    for (int c=0;c<4;c++){
      int idx = u*4+c;
      float val = (c==0)?x.x:(c==1)?x.y:(c==2)?x.z:x.w;
      bool masked = (idx==UNK) || (idx==EOS && t<=MIN_LEN);
      if (!masked && val > tv[7]){
        tv[7] = val; ti[7] = idx;
        #pragma unroll
        for (int j=7;j>0;j--){
          if (tv[j] > tv[j-1]){
            float tf=tv[j]; tv[j]=tv[j-1]; tv[j-1]=tf;
            int tii=ti[j]; ti[j]=ti[j-1]; ti[j-1]=tii;
          }
        }
      }
    }
  }
  rv[tid] = ls;
  #pragma unroll
  for (int j=0;j<8;j++){ mv[tid][j]=tv[j]; mi[tid][j]=ti[j]; }
  __syncthreads();
  for (int s2=128; s2; s2>>=1){ if (tid<s2) rv[tid]+=rv[tid+s2]; __syncthreads(); }
  for (int s2=128; s2; s2>>=1){
    if (tid < s2){
      float ra[8]; int ri_[8];
      int pa=0, pb=0;
      #pragma unroll
      for (int o=0;o<8;o++){
        float va = mv[tid][pa<8?pa:7];   int xa = mi[tid][pa<8?pa:7];
        float vb = mv[tid+s2][pb<8?pb:7]; int xb = mi[tid+s2][pb<8?pb:7];
        bool ava = (pa<8), avb = (pb<8);
        bool ta;
        if (!ava) ta = false;
        else if (!avb) ta = true;
        else ta = (va > vb) || (va == vb && xa < xb);
        ra[o] = ta ? va : vb; ri_[o] = ta ? xa : xb;
        pa += ta ? 1 : 0; pb += ta ? 0 : 1;
      }
      #pragma unroll
      for (int o=0;o<8;o++){ mv[tid][o]=ra[o]; mi[tid][o]=ri_[o]; }
    }
    __syncthreads();
  }
  if (tid == 0){
    float* pp = sc + PART_O + ((long long)n*4 + hc)*20;
    #pragma unroll
    for (int o=0;o<8;o++){ pp[o] = mv[0][o]; ((int*)pp)[8+o] = mi[0][o]; }
    pp[16] = rmax; pp[17] = rv[0];
  }
}

// ---------------- beam (proven R15: 4-partial merge prologue) ----------------
__global__ __launch_bounds__(64) void beam_k(float* sc, int t){
  int b = blockIdx.x, lane = threadIdx.x;
  int* endp = (int*)(sc + END_O);
  int* ltok = (int*)(sc + LTOK_O);
  const int* tokc; int* tokn; const float* bsc; float* bsn;
  if (t & 1){ tokc=(const int*)(sc+TOK0_O); tokn=(int*)(sc+TOK1_O); bsc=sc+BS0_O; bsn=sc+BS1_O; }
  else      { tokc=(const int*)(sc+TOK1_O); tokn=(int*)(sc+TOK0_O); bsc=sc+BS1_O; bsn=sc+BS0_O; }
  __shared__ float tks[64]; __shared__ int tki[64];
  __shared__ float l1v[64]; __shared__ int l1i[64];
  __shared__ float l2v[64]; __shared__ int l2i[64];
  __shared__ int selp[8]; __shared__ int newtok[8]; __shared__ float newsc[8]; __shared__ int newend[8];
  if (lane < 8){
    const float* p0 = sc + PART_O + ((long long)(b*8+lane)*4 + 0)*20;
    const float* p1 = p0 + 20;
    const float* p2 = p0 + 40;
    const float* p3 = p0 + 60;
    float m0=p0[16], m1=p1[16], m2=p2[16], m3=p3[16];
    float gm = fmaxf(fmaxf(m0,m1), fmaxf(m2,m3));
    float ss = p0[17]*expf(m0-gm) + p1[17]*expf(m1-gm) + p2[17]*expf(m2-gm) + p3[17]*expf(m3-gm);
    float lsum = logf(ss);
    int base = lane*8;
    {
      int pa=0, pb=0;
      for (int o=0;o<8;o++){
        int ia = pa<8?pa:7, ib = pb<8?pb:7;
        float va = p0[ia]; int xa = ((const int*)p0)[8+ia];
        float vb = p1[ib]; int xb = ((const int*)p1)[8+ib];
        bool ta = (pa<8) && ((pb>=8) || (va > vb) || (va == vb && xa < xb));
        l1v[base+o] = ta?va:vb; l1i[base+o] = ta?xa:xb;
        pa += ta?1:0; pb += ta?0:1;
      }
    }
    {
      int pa=0, pb=0;
      for (int o=0;o<8;o++){
        int ia = pa<8?pa:7, ib = pb<8?pb:7;
        float va = p2[ia]; int xa = ((const int*)p2)[8+ia];
        float vb = p3[ib]; int xb = ((const int*)p3)[8+ib];
        bool ta = (pa<8) && ((pb>=8) || (va > vb) || (va == vb && xa < xb));
        l2v[base+o] = ta?va:vb; l2i[base+o] = ta?xa:xb;
        pa += ta?1:0; pb += ta?0:1;
      }
    }
    {
      int pa=0, pb=0;
      for (int o=0;o<8;o++){
        int ia = pa<8?pa:7, ib = pb<8?pb:7;
        float va = l1v[base+ia]; int xa = l1i[base+ia];
        float vb = l2v[base+ib]; int xb = l2i[base+ib];
        bool ta = (pa<8) && ((pb>=8) || (va > vb) || (va == vb && xa < xb));
        tks[base+o] = ((ta?va:vb) - gm) - lsum;
        tki[base+o] = ta?xa:xb;
        pa += ta?1:0; pb += ta?0:1;
      }
    }
  }
  __syncthreads();
  if (lane == 0){
    float tot[64]; float cur[64]; int tix[64];
    for (int k=0;k<8;k++){
      float tp = 0;
      for (int u=0;u<T;u++) tp += bsc[u*N + b*8 + k];
      int ek = endp[b*8+k];
      for (int j=0;j<8;j++){
        float scv = tks[k*8 + j];
        if (t > 1) scv -= DD * (float)j;
        float fin = ek ? (-scv + (j==0 ? 0.0f : FNEG)) : 0.0f;
        tot[k*8+j] = (scv + tp) + fin;
        cur[k*8+j] = scv + fin;
        tix[k*8+j] = tki[k*8 + j];
      }
    }
    for (int q=0;q<8;q++){
      int best = 0; float bv = tot[0];
      for (int c=1;c<64;c++){
        if (tot[c] > bv){ bv = tot[c]; best = c; }
      }
      int p = best >> 3;
      int en = endp[b*8+p];
      int tk2 = tix[best];
      int lt = en ? PAD : tk2;
      selp[q] = p;
      newtok[q] = lt;
      newsc[q] = (lt != PAD) ? cur[best] : 0.0f;
      newend[q] = (en || lt == EOS) ? 1 : 0;
      tot[best] = -INFINITY;
    }
  }
  __syncthreads();
  for (int u = lane; u < T*8; u += 64){
    int tp2 = u >> 3, jp = u & 7;
    int p = selp[jp];
    tokn[tp2*N + b*8 + jp] = tokc[tp2*N + b*8 + p];
    bsn[tp2*N + b*8 + jp]  = bsc[tp2*N + b*8 + p];
  }
  __syncthreads();
  if (lane < 8){
    tokn[t*N + b*8 + lane] = newtok[lane];
    bsn[t*N + b*8 + lane]  = newsc[lane];
    ltok[b*8+lane] = newtok[lane];
    endp[b*8+lane] = newend[lane];
  }
  const float4* hsrc = (const float4*)(sc + HNEW_O + (long long)(b*8)*H);
  float4* hdst = (float4*)(sc + HID_O + (long long)(b*8)*H);
  for (int u = lane; u < 8*128; u += 64){
    int jp = u >> 7, c = u & 127;
    hdst[jp*128 + c] = hsrc[c];
  }
}

// ---------------- emit tokens + beam_scores (proven; ordered before zero_k) ----------------
__global__ void emit_k(float* out, float* sc){
  int idx = blockIdx.x*256 + threadIdx.x;
  if (idx < T*N){
    out[TOK_OUT_OFF + idx] = (float)(((const int*)(sc + TOK1_O))[idx]);
    out[BS_OUT_OFF + idx]  = sc[BS1_O + idx];
  }
}

extern "C" void kernel_launch(void* const* d_in, const int* in_sizes, int n_in,
                              void* d_out, int out_size, void* d_ws, size_t ws_size,
                              hipStream_t stream){
  const int*   src    = (const int*)d_in[0];
  const int*   srclen = (const int*)d_in[1];
  const float* embed  = (const float*)d_in[2];
  const float* eWih   = (const float*)d_in[3];
  const float* eWhh   = (const float*)d_in[4];
  const float* ebih   = (const float*)d_in[5];
  const float* ebhh   = (const float*)d_in[6];
  const float* brW    = (const float*)d_in[7];
  const float* brb    = (const float*)d_in[8];
  const float* dWih   = (const float*)d_in[9];
  const float* dWhh   = (const float*)d_in[10];
  const float* dbih   = (const float*)d_in[11];
  const float* dbhh   = (const float*)d_in[12];
  const float* attW   = (const float*)d_in[13];
  const float* cmbW   = (const float*)d_in[14];
  const float* cmbb   = (const float*)d_in[15];
  const float* outW   = (const float*)d_in[16];
  const float* outb   = (const float*)d_in[17];
  float* sc = (float*)d_out;

  tr_k<<<dim3(16,48),256,0,stream>>>(eWih, sc+WTEIH_O, 1536, 512);
  tr_k<<<dim3(16,48),256,0,stream>>>(eWhh, sc+WTEHH_O, 1536, 512);
  tr_k<<<dim3(16,48),256,0,stream>>>(dWih, sc+WTDIH_O, 1536, 512);
  tr_k<<<dim3(16,48),256,0,stream>>>(dWhh, sc+WTDHH_O, 1536, 512);
  tr_k<<<dim3(16,16),256,0,stream>>>(attW, sc+WTATT_O, 512, 512);
  tr_k<<<dim3(32,16),256,0,stream>>>(cmbW, sc+WTCMB_O, 512, 1024);
  tr_k<<<dim3(16,16),256,0,stream>>>(brW,  sc+WTBRG_O, 512, 512);
  tr_k<<<dim3(16,1000),256,0,stream>>>(outW, sc+WTOUT_O, 32000, 512);
  init_k<<<64,256,0,stream>>>(sc);

  for (int t=0; t<S; t++)
    enc2_k<<<dim3(8,16),384,0,stream>>>(src, srclen, embed, sc+WTEIH_O, sc+WTEHH_O, ebih, ebhh, sc, t);
  bridge_k<<<16,256,0,stream>>>(sc+WTBRG_O, brb, sc);

  for (int t=1; t<T; t++){
    grudec_k<<<dim3(8,32),256,0,stream>>>(embed, sc+WTDIH_O, sc+WTDHH_O, dbih, dbhh, sc);
    qgemm_k<<<dim3(8,32),256,0,stream>>>(sc+WTATT_O, sc);
    att_k<<<dim3(2,128),256,0,stream>>>(srclen, sc);
    comb_k<<<dim3(8,32),256,0,stream>>>(sc+WTCMB_O, cmbb, sc);
    logits_k<<<dim3(32,8),256,0,stream>>>(sc+WTOUT_O, outb, sc);
    topkp_k<<<dim3(4,128),256,0,stream>>>(sc, t);
    beam_k<<<16,64,0,stream>>>(sc, t);
  }

  emit_k<<<20,256,0,stream>>>((float*)d_out, sc);
  zero_k<<<2048,256,0,stream>>>((float4*)d_out);
}